// Round 10
// baseline (268.146 us; speedup 1.0000x reference)
//
#include <hip/hip_runtime.h>

#define TLEN 4096
#define NQ (TLEN / 4)     // 1024 quads per row
#define NSHIFT 21
#define SHIFT 10
#define NTHR 256
#define PARTS 4           // kernel-A blocks per row (4 x 256 threads = 1024 quads)
#define NVAL 32           // padded value count (25 used: 21 sxy + sx,sxx,sy,syy)

// ---- Kernel A: per-quarter-row partial sums -------------------------------
// Block b: row = b>>2, part = b&3. Each thread owns exactly ONE quad
// (c = part*256+tid): 1 x-quad + 7 clamped/masked y-quads, 25 FMA sums,
// per-wave butterfly reduce-scatter, cross-wave LDS reduce, 32-float store.
// No tail loops -> short uniform blocks; 8192 blocks = 4 batches/CU so
// batches pipeline and hide each other's reduce/store tails.
__global__ __launch_bounds__(NTHR, 4)
void partial_kernel(const float* __restrict__ x, const float* __restrict__ y,
                    float* __restrict__ partial)
{
    __shared__ float redbuf[4][NVAL];

    const int tid  = threadIdx.x;
    const int row  = blockIdx.x >> 2;
    const int part = blockIdx.x & 3;
    const int lane = tid & 63;
    const int wid  = tid >> 6;

    const float4* xg = (const float4*)(x + (size_t)row * TLEN);
    const float4* yq = (const float4*)(y + (size_t)row * TLEN);
    const int c = part * NTHR + tid;          // quad index; elems i0 = 4c

    float4 xv4 = xg[c];
    float xv[4] = {xv4.x, xv4.y, xv4.z, xv4.w};

    // y window quads c-3..c+3 -> floats y[4c-12 .. 4c+15]; yw[0]=y[4c-12].
    // Shift range +-10 < 12 => OOB elements lie in fully-OOB quads; clamp+mask
    // reproduces zero-padding exactly with unconditional loads.
    float yw[28];
    #pragma unroll
    for (int k = 0; k < 7; ++k) {
        int qi = c + k - 3;
        int qc = qi < 0 ? 0 : (qi > NQ - 1 ? NQ - 1 : qi);
        float msk = (qi == qc) ? 1.f : 0.f;
        float4 v = yq[qc];
        yw[4*k+0] = v.x * msk; yw[4*k+1] = v.y * msk;
        yw[4*k+2] = v.z * msk; yw[4*k+3] = v.w * msk;
    }

    float sxy[NSHIFT];
    #pragma unroll
    for (int k = 0; k < NSHIFT; ++k) sxy[k] = 0.f;
    float sx = 0.f, sxx = 0.f, sy = 0.f, syy = 0.f;

    #pragma unroll
    for (int l = 0; l < 4; ++l) {
        float xl = xv[l];
        sx += xl; sxx = fmaf(xl, xl, sxx);
        float yl = yw[12 + l];
        sy += yl; syy = fmaf(yl, yl, syy);
        // y[i+s] at window offset l + (s+SHIFT) + 2
        #pragma unroll
        for (int si = 0; si < NSHIFT; ++si)
            sxy[si] = fmaf(xl, yw[l + si + 2], sxy[si]);
    }

    // per-wave butterfly reduce-scatter (33 shuffles); after rounds on lane
    // bits 5..1 + final xor-1 add, lane l holds full sum of value (l>>1)&31.
    float vals[32];
    #pragma unroll
    for (int k = 0; k < NSHIFT; ++k) vals[k] = sxy[k];
    vals[21] = sx; vals[22] = sxx; vals[23] = sy; vals[24] = syy;
    #pragma unroll
    for (int k = NSHIFT + 4; k < 32; ++k) vals[k] = 0.f;

    #pragma unroll
    for (int b = 5; b >= 1; --b) {
        const int mask = 1 << b;
        const int half = 1 << (b - 1);
        const bool keepLow = ((lane >> b) & 1) == 0;
        #pragma unroll
        for (int j = 0; j < half; ++j) {
            float send = keepLow ? vals[j + half] : vals[j];
            float recv = __shfl_xor(send, mask, 64);
            vals[j] = (keepLow ? vals[j] : vals[j + half]) + recv;
        }
    }
    {
        float recv = __shfl_xor(vals[0], 1, 64);
        float tot = vals[0] + recv;
        if ((lane & 1) == 0) redbuf[wid][(lane >> 1) & 31] = tot;
    }
    __syncthreads();

    if (wid == 0 && lane < 32) {
        float S = redbuf[0][lane] + redbuf[1][lane] + redbuf[2][lane] + redbuf[3][lane];
        partial[(size_t)blockIdx.x * NVAL + lane] = S;   // coalesced 128B store
    }
}

// ---- Kernel B: per-row Pearson + masked-MSE -------------------------------
// One wave per row: sum the 4 part-partials, lanes 0..20 each evaluate one
// shift (edge sums <=10 iters from L3-resident inputs), argmax shuffle with
// first-max tie-break, lane 0 writes mse[row].
__global__ __launch_bounds__(64)
void pearson_kernel(const float* __restrict__ x, const float* __restrict__ y,
                    const float* __restrict__ partial, float* __restrict__ mse_out)
{
    const int row  = blockIdx.x;
    const int lane = threadIdx.x;
    const int v = lane & 31;

    const float* xrow = x + (size_t)row * TLEN;
    const float* yrow = y + (size_t)row * TLEN;

    float S = 0.f;
    #pragma unroll
    for (int p = 0; p < PARTS; ++p)
        S += partial[(size_t)(row * PARTS + p) * NVAL + v];

    float Sx  = __shfl(S, 21, 64);
    float Sxx = __shfl(S, 22, 64);
    float Sy  = __shfl(S, 23, 64);
    float Syy = __shfl(S, 24, 64);

    float corr = -1e30f, mse = 0.f;
    int bsi = lane;
    if (lane < NSHIFT) {
        const int s = lane - SHIFT;
        const int k = s < 0 ? -s : s;
        float ax = 0.f, axx = 0.f, ay = 0.f, ayy = 0.f;
        if (s >= 0) {
            // drop last k of x, first k of y
            for (int j = 0; j < k; ++j) {
                float xv = xrow[TLEN - 1 - j];
                float yv = yrow[j];
                ax += xv; axx = fmaf(xv, xv, axx);
                ay += yv; ayy = fmaf(yv, yv, ayy);
            }
        } else {
            // drop first k of x, last k of y
            for (int j = 0; j < k; ++j) {
                float xv = xrow[j];
                float yv = yrow[TLEN - 1 - j];
                ax += xv; axx = fmaf(xv, xv, axx);
                ay += yv; ayy = fmaf(yv, yv, ayy);
            }
        }
        const float n = (float)(TLEN - k);
        float Sxs = Sx - ax, Sxxs = Sxx - axx;
        float Sys = Sy - ay, Syys = Syy - ayy;
        float Sxys = S;                 // lane si holds sxy[si]
        float cov = Sxys - Sxs * Sys / n;
        float vx  = Sxxs - Sxs * Sxs / n;
        float vy  = Syys - Sys * Sys / n;
        corr = cov * rsqrtf(vx * vy);
        mse  = (Sxxs + Syys - 2.f * Sxys) / n;
    }
    // argmax over lanes, first-max tie-break (smallest shift index)
    #pragma unroll
    for (int m = 32; m >= 1; m >>= 1) {
        float oc = __shfl_xor(corr, m, 64);
        float om = __shfl_xor(mse,  m, 64);
        int  osi = __shfl_xor(bsi,  m, 64);
        if (oc > corr || (oc == corr && osi < bsi)) {
            corr = oc; mse = om; bsi = osi;
        }
    }
    if (lane == 0) mse_out[row] = mse;
}

// ---- Kernel C: deterministic final mean over B rows -----------------------
__global__ __launch_bounds__(NTHR)
void finalize_kernel(const float* __restrict__ mse, float* __restrict__ out, int B)
{
    __shared__ float red[4];
    int tid = threadIdx.x;
    int lane = tid & 63, wid = tid >> 6;
    const float4* m4 = (const float4*)mse;
    float a = 0.f;
    for (int i = tid; i < B / 4; i += NTHR) {
        float4 v = m4[i];
        a += (v.x + v.y) + (v.z + v.w);
    }
    #pragma unroll
    for (int off = 32; off > 0; off >>= 1)
        a += __shfl_down(a, off, 64);
    if (lane == 0) red[wid] = a;
    __syncthreads();
    if (tid == 0) out[0] = (red[0] + red[1] + red[2] + red[3]) / (float)B;
}

extern "C" void kernel_launch(void* const* d_in, const int* in_sizes, int n_in,
                              void* d_out, int out_size, void* d_ws, size_t ws_size,
                              hipStream_t stream)
{
    const float* x = (const float*)d_in[0];
    const float* y = (const float*)d_in[1];
    float* out = (float*)d_out;
    const int B = in_sizes[0] / TLEN;

    float* partial = (float*)d_ws;                       // B*PARTS*NVAL floats (1 MB)
    float* mse     = partial + (size_t)B * PARTS * NVAL; // B floats

    partial_kernel<<<B * PARTS, NTHR, 0, stream>>>(x, y, partial);
    pearson_kernel<<<B, 64, 0, stream>>>(x, y, partial, mse);
    finalize_kernel<<<1, NTHR, 0, stream>>>(mse, out, B);
}

// Round 11
// 96.270 us; speedup vs baseline: 2.7853x; 2.7853x over previous
//
#include <hip/hip_runtime.h>

#define TLEN 4096
#define NQ (TLEN / 4)     // 1024 quads per row
#define NSHIFT 21
#define SHIFT 10
#define NTHR 256

// One block per row. Continuous-streaming design (measured best: round 7,
// total 96.4 us): no LDS staging, y window read directly via coalesced float4
// loads; 7 overlapping window reads hit L1/L2 (inputs largely L3-resident).
// OOB: shift range +-10 < 12 => OOB y elements lie in fully-OOB quads;
// branch-free clamp+mask reproduces reference zero-padding exactly with
// unconditional loads. launch_bounds(256,4): 128-VGPR budget fits the
// ~110-reg live set (measured VGPR=60, no spill).
// REVERTED (measured regressions): fused single-address atomicAdd (+~20 us
// serialized retirement tail, r9); 4-blocks/row split (AGPR/scratch codegen
// blowup, VALUBusy 110%, r10). Separate finalize kernel is the best measured.
__global__ __launch_bounds__(NTHR, 4)
void shift_corr_kernel(const float* __restrict__ x, const float* __restrict__ y,
                       float* __restrict__ mse_out)
{
    __shared__ float redbuf[4][32];

    const int tid  = threadIdx.x;
    const int row  = blockIdx.x;
    const int lane = tid & 63;
    const int wid  = tid >> 6;

    const float* xrow = x + (size_t)row * TLEN;
    const float* yrow = y + (size_t)row * TLEN;
    const float4* xg = (const float4*)xrow;
    const float4* yq = (const float4*)yrow;

    // preload x quads (coalesced, in flight while first y reads issue)
    float4 xq[4];
    #pragma unroll
    for (int it = 0; it < 4; ++it)
        xq[it] = xg[tid + it * NTHR];

    // ---- main pass: 21-lag cross-corr + full-row moment sums ----
    float sxy[NSHIFT];
    #pragma unroll
    for (int k = 0; k < NSHIFT; ++k) sxy[k] = 0.f;
    float sx = 0.f, sxx = 0.f, sy = 0.f, syy = 0.f;

    #pragma unroll
    for (int it = 0; it < 4; ++it) {
        const int c = tid + it * NTHR;    // quad index; elems i0 = 4c
        float xv[4] = {xq[it].x, xq[it].y, xq[it].z, xq[it].w};
        // y window quads c-3..c+3 -> floats y[4c-12 .. 4c+15]; yw[0]=y[4c-12]
        float yw[28];
        #pragma unroll
        for (int k = 0; k < 7; ++k) {
            int qi = c + k - 3;
            int qc = qi < 0 ? 0 : (qi > NQ - 1 ? NQ - 1 : qi);
            float msk = (qi == qc) ? 1.f : 0.f;   // 0 for fully-OOB quads
            float4 v = yq[qc];                    // unconditional load
            yw[4*k+0] = v.x * msk; yw[4*k+1] = v.y * msk;
            yw[4*k+2] = v.z * msk; yw[4*k+3] = v.w * msk;
        }
        #pragma unroll
        for (int l = 0; l < 4; ++l) {
            float xl = xv[l];
            sx += xl; sxx = fmaf(xl, xl, sxx);
            float yl = yw[12 + l];
            sy += yl; syy = fmaf(yl, yl, syy);
            // y[i+s] at window offset l + (s+SHIFT) + 2
            #pragma unroll
            for (int si = 0; si < NSHIFT; ++si)
                sxy[si] = fmaf(xl, yw[l + si + 2], sxy[si]);
        }
    }

    // ---- per-wave butterfly reduce-scatter: 33 shuffles total ----
    // After rounds on lane-bits 5..1, lane l holds value index (l>>1)&31.
    float vals[32];
    #pragma unroll
    for (int k = 0; k < NSHIFT; ++k) vals[k] = sxy[k];
    vals[21] = sx; vals[22] = sxx; vals[23] = sy; vals[24] = syy;
    #pragma unroll
    for (int k = NSHIFT + 4; k < 32; ++k) vals[k] = 0.f;

    #pragma unroll
    for (int b = 5; b >= 1; --b) {
        const int mask = 1 << b;
        const int half = 1 << (b - 1);
        const bool keepLow = ((lane >> b) & 1) == 0;
        #pragma unroll
        for (int j = 0; j < half; ++j) {
            float send = keepLow ? vals[j + half] : vals[j];
            float recv = __shfl_xor(send, mask, 64);
            vals[j] = (keepLow ? vals[j] : vals[j + half]) + recv;
        }
    }
    {   // lanes l and l^1 hold same value; final add gives full wave sum
        float recv = __shfl_xor(vals[0], 1, 64);
        float tot = vals[0] + recv;
        if ((lane & 1) == 0) redbuf[wid][(lane >> 1) & 31] = tot;
    }
    __syncthreads();

    // ---- wave 0: cross-wave sum + per-shift Pearson, wave-parallel ----
    if (wid == 0) {
        const int v = lane & 31;
        float S = redbuf[0][v] + redbuf[1][v] + redbuf[2][v] + redbuf[3][v];
        float Sx  = __shfl(S, 21, 64);
        float Sxx = __shfl(S, 22, 64);
        float Sy  = __shfl(S, 23, 64);
        float Syy = __shfl(S, 24, 64);

        float corr = -1e30f, mse = 0.f;
        int bsi = lane;
        if (lane < NSHIFT) {
            const int s = lane - SHIFT;
            const int k = s < 0 ? -s : s;
            float ax = 0.f, axx = 0.f, ay = 0.f, ayy = 0.f;
            if (s >= 0) {
                // drop last k of x, first k of y
                for (int j = 0; j < k; ++j) {
                    float xv = xrow[TLEN - 1 - j];
                    float yv = yrow[j];
                    ax += xv; axx = fmaf(xv, xv, axx);
                    ay += yv; ayy = fmaf(yv, yv, ayy);
                }
            } else {
                // drop first k of x, last k of y
                for (int j = 0; j < k; ++j) {
                    float xv = xrow[j];
                    float yv = yrow[TLEN - 1 - j];
                    ax += xv; axx = fmaf(xv, xv, axx);
                    ay += yv; ayy = fmaf(yv, yv, ayy);
                }
            }
            const float n = (float)(TLEN - k);
            float Sxs = Sx - ax, Sxxs = Sxx - axx;
            float Sys = Sy - ay, Syys = Syy - ayy;
            float Sxys = S;                 // lane si holds sxy[si]
            float cov = Sxys - Sxs * Sys / n;
            float vx  = Sxxs - Sxs * Sxs / n;
            float vy  = Syys - Sys * Sys / n;
            corr = cov * rsqrtf(vx * vy);
            mse  = (Sxxs + Syys - 2.f * Sxys) / n;
        }
        // argmax over lanes, first-max tie-break (smallest shift index)
        #pragma unroll
        for (int m = 32; m >= 1; m >>= 1) {
            float oc = __shfl_xor(corr, m, 64);
            float om = __shfl_xor(mse,  m, 64);
            int  osi = __shfl_xor(bsi,  m, 64);
            if (oc > corr || (oc == corr && osi < bsi)) {
                corr = oc; mse = om; bsi = osi;
            }
        }
        if (lane == 0) mse_out[row] = mse;
    }
}

// Deterministic final mean over B rows (float4 loads).
__global__ __launch_bounds__(NTHR)
void finalize_kernel(const float* __restrict__ mse, float* __restrict__ out, int B)
{
    __shared__ float red[4];
    int tid = threadIdx.x;
    int lane = tid & 63, wid = tid >> 6;
    const float4* m4 = (const float4*)mse;
    float a = 0.f;
    for (int i = tid; i < B / 4; i += NTHR) {
        float4 v = m4[i];
        a += (v.x + v.y) + (v.z + v.w);
    }
    #pragma unroll
    for (int off = 32; off > 0; off >>= 1)
        a += __shfl_down(a, off, 64);
    if (lane == 0) red[wid] = a;
    __syncthreads();
    if (tid == 0) out[0] = (red[0] + red[1] + red[2] + red[3]) / (float)B;
}

extern "C" void kernel_launch(void* const* d_in, const int* in_sizes, int n_in,
                              void* d_out, int out_size, void* d_ws, size_t ws_size,
                              hipStream_t stream)
{
    const float* x = (const float*)d_in[0];
    const float* y = (const float*)d_in[1];
    float* out = (float*)d_out;
    float* ws  = (float*)d_ws;
    const int B = in_sizes[0] / TLEN;

    shift_corr_kernel<<<B, NTHR, 0, stream>>>(x, y, ws);
    finalize_kernel<<<1, NTHR, 0, stream>>>(ws, out, B);
}